// Round 1
// baseline (324.925 us; speedup 1.0000x reference)
//
#include <hip/hip_runtime.h>

// ---------------------------------------------------------------------------
// X:(16,4096,512) -> M=65536 rows. enc1 K=512 N=256, d=64.
// h=511 patches/batch, 512 8-row groups/batch (patch i = groups i,i+1).
// Xe is never needed per-element: only per-patch means -> per-group sums Gs.
// ---------------------------------------------------------------------------

typedef __attribute__((ext_vector_type(8))) _Float16 half8;
typedef __attribute__((ext_vector_type(4))) _Float16 half4;
typedef __attribute__((ext_vector_type(4))) float floatx4;

__device__ __forceinline__ _Float16 f2h(float f) { return (_Float16)f; }

#define MFMA16(A, B, C) __builtin_amdgcn_mfma_f32_16x16x32_f16((A), (B), (C), 0, 0, 0)

// ---------------------------------------------------------------------------
// Prep: weights -> fp16 K-major: W1t[256][512], W2t[64][256], Wdt[512][64]
// ---------------------------------------------------------------------------
__global__ __launch_bounds__(256) void prep_weights(
    const float* __restrict__ W1, const float* __restrict__ W2,
    const float* __restrict__ Wd,
    _Float16* __restrict__ W1t, _Float16* __restrict__ W2t,
    _Float16* __restrict__ Wdt)
{
    int idx = blockIdx.x * 256 + threadIdx.x;           // 512 blocks -> 131072
    { int n = idx >> 9, k = idx & 511;  W1t[idx] = f2h(W1[k * 256 + n]); }
    if (idx < 16384) { int n = idx >> 8, k = idx & 255; W2t[idx] = f2h(W2[k * 64 + n]); }
    if (idx < 32768) { int n = idx >> 6, k = idx & 63;  Wdt[idx] = f2h(Wd[k * 512 + n]); }
}

// ---------------------------------------------------------------------------
// enc_fused: Gs[8 groups][64] per 64-row block.
//  Stage 1 (K=512, BK=32, DOUBLE-BUFFERED 2-phase pipeline):
//   per iter: issue next W1t tile via global_load_lds into Balt, repack next
//   X tile into Aalt (VALU), then MFMA current tile, then ONE barrier.
//   The vmcnt(0) drain at the barrier lands AFTER the MFMA phase, so the
//   W1t L2 latency is covered by compute (T3-minimum schedule).
//   Bs swizzle: stored[R][ch] = logical[R][ch ^ ((R>>1)&3)], 16B chunks.
//   Applied on the pre-swizzled global source AND the ds_read (rule #21);
//   af reads land <=2-way bank conflicts (free). As padded to 40 halves.
//  Group-reduce: leaky(hidden+b1), butterfly shfl_xor(1,2,4) sums m over each
//   8-row group, writers (lane&7)==0 -> Hsum fp16 LDS.
//  Stage 2: Gs = Hsum[8pad16][256] @ W2 + 8*b2 -- garbage Hsum rows 8-15 only
//   affect D rows 8-15 (never stored).
// ---------------------------------------------------------------------------
__global__ __launch_bounds__(256) void enc_fused(
    const float* __restrict__ X, const _Float16* __restrict__ W1t,
    const float* __restrict__ b1, const _Float16* __restrict__ W2t,
    const float* __restrict__ b2, float* __restrict__ Gs)
{
    __shared__ _Float16 smem[21504];            // 43008 B -> 3 blocks/CU
    _Float16* As0  = smem;                      // [64][40]
    _Float16* As1  = smem + 2560;               // [64][40]
    _Float16* Bs0  = smem + 5120;               // [256][32] (chunk-swizzled)
    _Float16* Bs1  = smem + 13312;              // [256][32]
    _Float16* Hs16 = smem;                      // [16][264] stage 2 (rows 0-7 valid)

    const int tid  = threadIdx.x;
    const int lane = tid & 63;
    const int w    = tid >> 6;
    const int m0   = blockIdx.x * 64;

    const int arow = tid >> 2;                   // 0..63
    const int acol = (tid & 3) << 3;             // 0,8,16,24 (floats within BK=32)
    const float* Abase = X + (size_t)(m0 + arow) * 512 + acol;

    floatx4 acc1[4][4];
#pragma unroll
    for (int ci = 0; ci < 4; ci++)
#pragma unroll
        for (int mi = 0; mi < 4; mi++) acc1[ci][mi] = (floatx4){0.f, 0.f, 0.f, 0.f};

    float4 pa0, pa1;
    auto loadA = [&](int kt) {
        pa0 = *(const float4*)(Abase + kt);
        pa1 = *(const float4*)(Abase + kt + 4);
    };
    auto writeAs = [&](_Float16* Ad) {
        half8 o;
        o[0] = f2h(pa0.x); o[1] = f2h(pa0.y); o[2] = f2h(pa0.z); o[3] = f2h(pa0.w);
        o[4] = f2h(pa1.x); o[5] = f2h(pa1.y); o[6] = f2h(pa1.z); o[7] = f2h(pa1.w);
        *(half8*)(Ad + arow * 40 + acol) = o;
    };
    // Stage W1t tile [256][kt..kt+32) into Bd: 16 calls of 1KB (16 rows x 64B);
    // wave w does rows 64w..64w+63. Lane l -> row base+(l>>2), chunk l&3.
    // Source pre-swizzled by (R>>1)&3 so ds_read side is ~conflict-free.
    auto issueB = [&](_Float16* Bd, int kt) {
#pragma unroll
        for (int q = 0; q < 4; q++) {
            const int base_row = (w << 6) + (q << 4);
            const int R  = base_row + (lane >> 2);
            const int ch = lane & 3;
            const _Float16* src = W1t + (size_t)R * 512 + kt + ((ch ^ ((R >> 1) & 3)) << 3);
            __builtin_amdgcn_global_load_lds(
                (const __attribute__((address_space(1))) unsigned int*)src,
                (__attribute__((address_space(3))) unsigned int*)(Bd + base_row * 32),
                16, 0, 0);
        }
    };

    auto STEP = [&](_Float16* Ac, _Float16* Bc, _Float16* Aa, _Float16* Ba, int it) {
        const int kt = it << 5;
        if (it < 15) {
            issueB(Ba, kt + 32);     // DMA in flight across MFMA phase
            writeAs(Aa);             // consumes pa (waits only the X loads)
            if (it < 14) loadA(kt + 64);
        }
        const int kc  = lane >> 4;   // 0..3: k-chunk this lane feeds MFMA
        half8 af[4], bf[4];
#pragma unroll
        for (int ci = 0; ci < 4; ci++) {
            const int c = (w << 6) + ci * 16 + (lane & 15);
            af[ci] = *(const half8*)&Bc[c * 32 + ((kc ^ ((c >> 1) & 3)) << 3)];
        }
#pragma unroll
        for (int mi = 0; mi < 4; mi++)
            bf[mi] = *(const half8*)&Ac[(mi * 16 + (lane & 15)) * 40 + (kc << 3)];
#pragma unroll
        for (int ci = 0; ci < 4; ci++)
#pragma unroll
            for (int mi = 0; mi < 4; mi++)
                acc1[ci][mi] = MFMA16(af[ci], bf[mi], acc1[ci][mi]);
        __syncthreads();             // single drain per K-step, after compute
    };

    // prologue
    loadA(0);
    issueB(Bs0, 0);
    writeAs(As0);
    loadA(32);
    __syncthreads();

    for (int it = 0; it < 16; it += 2) {
        STEP(As0, Bs0, As1, Bs1, it);
        STEP(As1, Bs1, As0, Bs0, it + 1);
    }

    // ---- group-reduce: Hsum[g][c] = sum_{m in g} leaky(hidden[m][c]+b1[c]) ----
    float4 b1v[4];
#pragma unroll
    for (int ci = 0; ci < 4; ci++)
        b1v[ci] = *(const float4*)&b1[(w << 6) + ci * 16 + ((lane >> 4) << 2)];
#pragma unroll
    for (int ci = 0; ci < 4; ci++) {
#pragma unroll
        for (int mi = 0; mi < 4; mi++) {
            float vs[4];
#pragma unroll
            for (int r = 0; r < 4; r++) {
                float v = acc1[ci][mi][r] + ((const float*)&b1v[ci])[r];
                vs[r] = v > 0.f ? v : 0.01f * v;
            }
#pragma unroll
            for (int r = 0; r < 4; r++) {
                vs[r] += __shfl_xor(vs[r], 1);
                vs[r] += __shfl_xor(vs[r], 2);
                vs[r] += __shfl_xor(vs[r], 4);
            }
            if ((lane & 7) == 0) {
                const int gl = 2 * mi + ((lane & 15) >> 3);
                half4 hv;
#pragma unroll
                for (int r = 0; r < 4; r++) hv[r] = f2h(vs[r]);
                *(half4*)&Hs16[gl * 264 + (w << 6) + ci * 16 + ((lane >> 4) << 2)] = hv;
            }
        }
    }
    __syncthreads();

    // ---- stage 2: Gs = Hsum @ W2 + 8*b2 (each wave: 16 out-channels) ----
    floatx4 acc2 = (floatx4){0.f, 0.f, 0.f, 0.f};
    const int kq = (lane >> 4) << 3;
#pragma unroll
    for (int ks = 0; ks < 8; ks++) {
        half8 af = *(const half8*)&Hs16[(lane & 15) * 264 + ks * 32 + kq];
        half8 bf = *(const half8*)&W2t[(size_t)((w << 4) + (lane & 15)) * 256 + ks * 32 + kq];
        acc2 = MFMA16(af, bf, acc2);
    }
    if (lane < 32) {
        const int n = (w << 4) + (lane & 15);
        const float bb = 8.f * b2[n];
        const int gbase = blockIdx.x * 8;
#pragma unroll
        for (int r = 0; r < 4; r++) {
            const int g = ((lane >> 4) << 2) + r;          // 0..7
            Gs[(size_t)(gbase + g) * 64 + n] = acc2[r] + bb;
        }
    }
}

// ---------------------------------------------------------------------------
// Patch attention: one wave per patch-row n, 4 waves/block.
// pp = (Gs[b*512+i] + Gs[b*512+i+1]) / 16.
// ---------------------------------------------------------------------------
#define TOP8_INS(mv) do { float _x = (mv); float _t;            \
    _t = fmaxf(s0,_x); _x = fminf(s0,_x); s0 = _t;              \
    _t = fmaxf(s1,_x); _x = fminf(s1,_x); s1 = _t;              \
    _t = fmaxf(s2,_x); _x = fminf(s2,_x); s2 = _t;              \
    _t = fmaxf(s3,_x); _x = fminf(s3,_x); s3 = _t;              \
    _t = fmaxf(s4,_x); _x = fminf(s4,_x); s4 = _t;              \
    _t = fmaxf(s5,_x); _x = fminf(s5,_x); s5 = _t;              \
    _t = fmaxf(s6,_x); _x = fminf(s6,_x); s6 = _t;              \
    s7 = fmaxf(s7,_x); } while (0)

__global__ __launch_bounds__(256) void patch_attn(
    const float* __restrict__ Gs,  const float* __restrict__ Wq,
    const float* __restrict__ Wk,  const float* __restrict__ Wv,
    const float* __restrict__ Wagg, const float* __restrict__ bagg,
    float* __restrict__ zout)
{
    __shared__ float sh[4][336];
    const int w    = threadIdx.x >> 6;
    const int lane = threadIdx.x & 63;
    const int n = blockIdx.x * 4 + w;   // 2044*4 = 8176
    const int b = n / 511;
    const int i = n - b * 511;
    float* pp  = &sh[w][0];
    float* qs  = pp + 64;
    float* ksm = pp + 128;
    float* vsm = pp + 192;
    float* avs = pp + 256;

    const float* gp = Gs + ((size_t)(b * 512 + i)) * 64 + lane;
    pp[lane] = (gp[0] + gp[64]) * 0.0625f;
    __syncthreads();

    float q = 0.f, k = 0.f, v = 0.f;
#pragma unroll 4
    for (int e = 0; e < 64; e += 4) {
        float4 p4 = *(const float4*)&pp[e];
        q = fmaf(p4.x, Wq[(e+0)*64+lane], q); q = fmaf(p4.y, Wq[(e+1)*64+lane], q);
        q = fmaf(p4.z, Wq[(e+2)*64+lane], q); q = fmaf(p4.w, Wq[(e+3)*64+lane], q);
        k = fmaf(p4.x, Wk[(e+0)*64+lane], k); k = fmaf(p4.y, Wk[(e+1)*64+lane], k);
        k = fmaf(p4.z, Wk[(e+2)*64+lane], k); k = fmaf(p4.w, Wk[(e+3)*64+lane], k);
        v = fmaf(p4.x, Wv[(e+0)*64+lane], v); v = fmaf(p4.y, Wv[(e+1)*64+lane], v);
        v = fmaf(p4.z, Wv[(e+2)*64+lane], v); v = fmaf(p4.w, Wv[(e+3)*64+lane], v);
    }
    float sq = q * q, sk = k * k;
#pragma unroll
    for (int o = 1; o < 64; o <<= 1) { sq += __shfl_xor(sq, o); sk += __shfl_xor(sk, o); }
    const float qni = q / (sqrtf(sq) + 1e-8f);
    const float kni = k / (sqrtf(sk) + 1e-8f);
    qs[lane] = qni; ksm[lane] = kni; vsm[lane] = v;
    __syncthreads();

    auto MV = [&](float kj, float qj) { return fmaf(qni, kj, -(kni * qj)); };

    float s0=-1e30f,s1=-1e30f,s2=-1e30f,s3=-1e30f,s4=-1e30f,s5=-1e30f,s6=-1e30f,s7=-1e30f;
#pragma unroll
    for (int j = 0; j < 64; j += 4) {
        float4 k4 = *(const float4*)&ksm[j];
        float4 q4 = *(const float4*)&qs[j];
        TOP8_INS(MV(k4.x, q4.x)); TOP8_INS(MV(k4.y, q4.y));
        TOP8_INS(MV(k4.z, q4.z)); TOP8_INS(MV(k4.w, q4.w));
    }
    const float teff = fmaxf(s7, 1e-37f) * (1.f - 1.2e-7f);

    float ssum = 0.f, av = 0.f;
#pragma unroll
    for (int j = 0; j < 64; j += 4) {
        float4 k4 = *(const float4*)&ksm[j];
        float4 q4 = *(const float4*)&qs[j];
        float4 v4 = *(const float4*)&vsm[j];
#define P2(KJ, QJ, VJ) do { float _m = MV(KJ, QJ); float _x2 = _m * _m;           \
        float _a = _m * (15.f + _x2) * __builtin_amdgcn_rcpf(fmaf(6.f, _x2, 15.f)); \
        float _am = (_m >= teff) ? _a : 0.f;                                       \
        ssum += _am; av = fmaf(_am, (VJ), av); } while (0)
        P2(k4.x, q4.x, v4.x); P2(k4.y, q4.y, v4.y);
        P2(k4.z, q4.z, v4.z); P2(k4.w, q4.w, v4.w);
#undef P2
    }
    avs[lane] = av / fmaxf(ssum, 1e-8f);
    __syncthreads();

    float zc = bagg[lane];
#pragma unroll 4
    for (int e = 0; e < 64; e += 4) {
        float4 a4 = *(const float4*)&avs[e];
        zc = fmaf(a4.x, Wagg[(e+0)*64+lane], zc); zc = fmaf(a4.y, Wagg[(e+1)*64+lane], zc);
        zc = fmaf(a4.z, Wagg[(e+2)*64+lane], zc); zc = fmaf(a4.w, Wagg[(e+3)*64+lane], zc);
    }
    zc = zc > 0.f ? zc : 0.01f * zc;
    zout[(size_t)n * 64 + lane] = zc;
}

// ---------------------------------------------------------------------------
// dec_fused: out[128x128 tile] = blend2(z)[128x64] @ Wd + bd.
// C written DIRECTLY from MFMA fragments (dword stores, 4x64B segments/instr,
// write-combined in L2) -- no LDS round-trip, no epilogue barriers.
// ---------------------------------------------------------------------------
__global__ __launch_bounds__(256) void dec_fused(
    const float* __restrict__ z, const _Float16* __restrict__ Wdt,
    const float* __restrict__ bd, float* __restrict__ out)
{
    __shared__ _Float16 As[128 * 72];
    __shared__ _Float16 Bs[128 * 72];
    const int tid  = threadIdx.x;
    const int lane = tid & 63;
    const int w    = tid >> 6;
    const int m0 = blockIdx.y * 128, n0 = blockIdx.x * 128;
    const int wrow = (w & 1) << 6, wcol = (w >> 1) << 6;

    {
        const int arow  = tid >> 1;
        const int akseg = (tid & 1) << 5;
        const int row = m0 + arow;
        const int b = row >> 12, l = row & 4095, g = l >> 3;
        const int g0 = g - 1 >= 0 ? g - 1 : 0;
        const int g1 = g <= 510 ? g : 510;
        const float w0 = (g >= 1) ? 1.f : 0.f;
        const float w1 = (g <= 510) ? 1.f : 0.f;
        const float sc = (w0 + w1) > 1.5f ? 0.5f : 1.f;
        const float* z0 = z + ((size_t)(b * 511 + g0)) * 64 + akseg;
        const float* z1 = z + ((size_t)(b * 511 + g1)) * 64 + akseg;
        _Float16* d = &As[arow * 72 + akseg];
#pragma unroll
        for (int u = 0; u < 4; u++) {
            float4 f0a = *(const float4*)(z0 + 8 * u);
            float4 f0b = *(const float4*)(z0 + 8 * u + 4);
            float4 f1a = *(const float4*)(z1 + 8 * u);
            float4 f1b = *(const float4*)(z1 + 8 * u + 4);
            half8 o;
            o[0] = f2h((f0a.x * w0 + f1a.x * w1) * sc);
            o[1] = f2h((f0a.y * w0 + f1a.y * w1) * sc);
            o[2] = f2h((f0a.z * w0 + f1a.z * w1) * sc);
            o[3] = f2h((f0a.w * w0 + f1a.w * w1) * sc);
            o[4] = f2h((f0b.x * w0 + f1b.x * w1) * sc);
            o[5] = f2h((f0b.y * w0 + f1b.y * w1) * sc);
            o[6] = f2h((f0b.z * w0 + f1b.z * w1) * sc);
            o[7] = f2h((f0b.w * w0 + f1b.w * w1) * sc);
            *(half8*)(d + 8 * u) = o;
        }
    }
    {
        const int brow  = tid >> 1;
        const int bkseg = (tid & 1) << 5;
        const _Float16* s = Wdt + (size_t)(n0 + brow) * 64 + bkseg;
        _Float16* d = &Bs[brow * 72 + bkseg];
#pragma unroll
        for (int u = 0; u < 4; u++) *(half8*)(d + 8 * u) = *(const half8*)(s + 8 * u);
    }
    __syncthreads();

    floatx4 accf[4][4];
#pragma unroll
    for (int mi = 0; mi < 4; mi++)
#pragma unroll
        for (int ni = 0; ni < 4; ni++) accf[mi][ni] = (floatx4){0.f, 0.f, 0.f, 0.f};
#pragma unroll
    for (int ks = 0; ks < 2; ks++) {
        const int koff = ks * 32 + ((lane >> 4) << 3);
        half8 af[4], bf[4];
#pragma unroll
        for (int mi = 0; mi < 4; mi++)
            af[mi] = *(const half8*)&As[(wrow + mi * 16 + (lane & 15)) * 72 + koff];
#pragma unroll
        for (int ni = 0; ni < 4; ni++)
            bf[ni] = *(const half8*)&Bs[(wcol + ni * 16 + (lane & 15)) * 72 + koff];
#pragma unroll
        for (int mi = 0; mi < 4; mi++)
#pragma unroll
            for (int ni = 0; ni < 4; ni++)
                accf[mi][ni] = MFMA16(af[mi], bf[ni], accf[mi][ni]);
    }

    float bvv[4];
#pragma unroll
    for (int ni = 0; ni < 4; ni++) bvv[ni] = bd[n0 + wcol + ni * 16 + (lane & 15)];

    // direct stores: row = m0+wrow+mi*16+(lane>>4)*4+r, col = n0+wcol+ni*16+(lane&15)
#pragma unroll
    for (int mi = 0; mi < 4; mi++) {
        const int row = m0 + wrow + mi * 16 + ((lane >> 4) << 2);
#pragma unroll
        for (int r = 0; r < 4; r++) {
            float* orow = out + (size_t)(row + r) * 512 + n0 + wcol + (lane & 15);
#pragma unroll
            for (int ni = 0; ni < 4; ni++)
                orow[ni * 16] = accf[mi][ni][r] + bvv[ni];
        }
    }
}

// ---------------------------------------------------------------------------
extern "C" void kernel_launch(void* const* d_in, const int* in_sizes, int n_in,
                              void* d_out, int out_size, void* d_ws, size_t ws_size,
                              hipStream_t stream)
{
    const float* X    = (const float*)d_in[0];
    const float* W1   = (const float*)d_in[1];
    const float* b1   = (const float*)d_in[2];
    const float* W2   = (const float*)d_in[3];
    const float* b2   = (const float*)d_in[4];
    const float* Wq   = (const float*)d_in[5];
    const float* Wk   = (const float*)d_in[6];
    const float* Wv   = (const float*)d_in[7];
    const float* Wagg = (const float*)d_in[8];
    const float* bagg = (const float*)d_in[9];
    const float* Wd   = (const float*)d_in[10];
    const float* bd   = (const float*)d_in[11];

    char* ws = (char*)d_ws;
    float*    Gs  = (float*)(ws);                  // 8192x64 f32  2,097,152 B
    float*    z   = (float*)(ws + 2097152);        // 8176x64 f32  2,093,056 B
    _Float16* W1t = (_Float16*)(ws + 4194304);     // 256x512 fp16   262,144 B
    _Float16* W2t = (_Float16*)(ws + 4456448);     // 64x256  fp16    32,768 B
    _Float16* Wdt = (_Float16*)(ws + 4489216);     // 512x64  fp16    65,536 B
    float* out = (float*)d_out;

    prep_weights<<<512, 256, 0, stream>>>(W1, W2, Wd, W1t, W2t, Wdt);
    enc_fused<<<1024, 256, 0, stream>>>(X, W1t, b1, W2t, b2, Gs);
    patch_attn<<<2044, 256, 0, stream>>>(Gs, Wq, Wk, Wv, Wagg, bagg, z);
    dec_fused<<<dim3(4, 512), 256, 0, stream>>>(z, Wdt, bd, out);
}